// Round 6
// baseline (433.927 us; speedup 1.0000x reference)
//
#include <hip/hip_runtime.h>
#include <hip/hip_bf16.h>
#include <cstdint>

#define D 128
#define LDSPITCH 136   // shorts; 272B row stride: 16B-aligned, banks uniform
#define ECAP 2048      // coarse-bucket capacity: E/NB ~ 1534, sd ~ 39 -> 13 sigma

typedef __attribute__((ext_vector_type(4))) float f32x4;
typedef __attribute__((ext_vector_type(8))) short s16x8;

__device__ __forceinline__ unsigned short f2b(float f) {
    union { float f; uint32_t u; } v; v.f = f;
    uint32_t b = v.u + 0x7fffu + ((v.u >> 16) & 1u);   // RNE
    return (unsigned short)(b >> 16);
}
__device__ __forceinline__ float b2f(unsigned short u) {
    union { uint32_t u; float f; } v; v.u = ((uint32_t)u) << 16; return v.f;
}

// ---- prep: [0,192) transpose+bf16 weights; 192: consts + zero coarse counters
__global__ __launch_bounds__(256) void k_prep(
    const float* __restrict__ fp_w, const float* __restrict__ lin_l_w,
    const float* __restrict__ lin_r_w,
    unsigned short* __restrict__ Btf, unsigned short* __restrict__ Btl,
    unsigned short* __restrict__ Btr,
    const float* __restrict__ res_w, const float* __restrict__ res_b,
    const float* __restrict__ sh_w, const float* __restrict__ sh_b,
    const float* __restrict__ alpha, float* __restrict__ c1, float* __restrict__ scal,
    int* __restrict__ ccnt, int NB) {
    int bid = blockIdx.x, tid = threadIdx.x;
    if (bid < 192) {
        int m = bid >> 6;
        int i = (bid & 63) * 256 + tid;
        const float* src = (m == 0) ? fp_w : (m == 1) ? lin_l_w : lin_r_w;
        unsigned short* dst = (m == 0) ? Btf : (m == 1) ? Btl : Btr;
        int k = i >> 7, n = i & 127;
        dst[n * D + k] = f2b(src[k * D + n]);
    } else {
        for (int j = tid; j < NB; j += 256) ccnt[j] = 0;
        if (tid < 128) {
            float s = 0.f;
            for (int j = 0; j < D; ++j) s += res_w[tid * D + j] * sh_w[j];
            c1[tid] = s;
            if (tid == 0) {
                float c0 = 0.f;
                for (int j = 0; j < D; ++j) c0 += res_b[j] * sh_w[j];
                c0 += sh_b[0];
                float a = 1.f / (1.f + expf(-alpha[0]));
                scal[0] = a; scal[1] = c0;
            }
        }
    }
}

// ---- GEMM1 (+ coarse edge partition piggy-backed):
// blocks [0,mb): xf = [x|pos|len] @ fp_w + fp_b -> bf16 xb; d1 = xf.c1
// blocks [mb,..): phase-1 counting sort — bucket = dst>>8 (391 HOT counters,
// L2/L3-pipelined) and contiguous (src,dst) appends (line-local writes),
// replacing 600k random-line cursor RMWs + scatter stores.
__global__ __launch_bounds__(256) void k_gemm1(
    const float* __restrict__ x, unsigned short* __restrict__ xb,
    const int* __restrict__ positions, const int* __restrict__ lengths,
    const unsigned short* __restrict__ Btf,
    const float* __restrict__ fp_w, const float* __restrict__ fp_b,
    const float* __restrict__ c1, float* __restrict__ d1, int N, int mb,
    const int* __restrict__ ei, int* __restrict__ ccnt, int2* __restrict__ coarse, int E) {
    if (blockIdx.x >= mb) {
        int e = (blockIdx.x - mb) * 256 + threadIdx.x;
        if (e < E) {
            int src = ei[e];
            int dst = ei[E + e];
            int b = dst >> 8;
            int pos = atomicAdd(&ccnt[b], 1);
            if (pos < ECAP) coarse[(size_t)b * ECAP + pos] = make_int2(src, dst);
        }
        return;
    }
    int lane = threadIdx.x & 63;
    int wv = threadIdx.x >> 6;
    int col = lane & 15, q = lane >> 4;
    int row0 = blockIdx.x * 64 + wv * 16;
    int arow = row0 + col; if (arow > N - 1) arow = N - 1;

    f32x4 acc[8];
#pragma unroll
    for (int nt = 0; nt < 8; ++nt) acc[nt] = (f32x4){0.f, 0.f, 0.f, 0.f};

#pragma unroll
    for (int ks = 0; ks < 4; ++ks) {
        const float* xp = x + (size_t)arow * D + ks * 32 + q * 8;
        float4 a0 = *(const float4*)xp;
        float4 a1 = *(const float4*)(xp + 4);
        s16x8 af;
        af[0] = (short)f2b(a0.x); af[1] = (short)f2b(a0.y);
        af[2] = (short)f2b(a0.z); af[3] = (short)f2b(a0.w);
        af[4] = (short)f2b(a1.x); af[5] = (short)f2b(a1.y);
        af[6] = (short)f2b(a1.z); af[7] = (short)f2b(a1.w);
#pragma unroll
        for (int nt = 0; nt < 8; ++nt) {
            s16x8 bf = *(const s16x8*)(Btf + (size_t)(nt * 16 + col) * D + ks * 32 + q * 8);
            acc[nt] = __builtin_amdgcn_mfma_f32_16x16x32_bf16(af, bf, acc[nt], 0, 0, 0);
        }
    }

    float pf[4], lf[4];
#pragma unroll
    for (int r = 0; r < 4; ++r) {
        int rr = row0 + q * 4 + r; int rc = rr < N ? rr : N - 1;
        pf[r] = (float)positions[rc] * (1.0f / 50.0f);
        lf[r] = (float)lengths[rc] * (1.0f / 500.0f);
    }
    float sdot[4] = {0.f, 0.f, 0.f, 0.f};
#pragma unroll
    for (int nt = 0; nt < 8; ++nt) {
        int n = nt * 16 + col;
        float bias = fp_b[n];
        float w128 = fp_w[128 * D + n];
        float w129 = fp_w[129 * D + n];
        float c1v = c1[n];
#pragma unroll
        for (int r = 0; r < 4; ++r) {
            float t = acc[nt][r] + bias + pf[r] * w128 + lf[r] * w129;
            int rr = row0 + q * 4 + r;
            if (rr < N) xb[(size_t)rr * D + n] = f2b(t);
            sdot[r] += t * c1v;
        }
    }
#pragma unroll
    for (int r = 0; r < 4; ++r) {
        float s = sdot[r];
        s += __shfl_xor(s, 1, 64);
        s += __shfl_xor(s, 2, 64);
        s += __shfl_xor(s, 4, 64);
        s += __shfl_xor(s, 8, 64);
        if (col == 0) {
            int rr = row0 + q * 4 + r;
            if (rr < N) d1[rr] = s;
        }
    }
}

// ---- phase-2 counting sort: per coarse bucket (256 nodes), LDS-stage pairs,
// LDS-histogram local dst, prefix-scan, emit dense CSR (rp + csr), coalesced.
__global__ __launch_bounds__(256) void k_bucket(
    const int2* __restrict__ coarse, const int* __restrict__ ccnt,
    int* __restrict__ csr, int* __restrict__ rp, int NB, int N) {
    __shared__ int2 pb[ECAP];         // 16 KB
    __shared__ int hist[256];
    __shared__ int epfx[256];
    __shared__ int slot[256];
    __shared__ int red[256];
    int tid = threadIdx.x, b = blockIdx.x;
    int cnt = ccnt[b]; if (cnt > ECAP) cnt = ECAP;

    for (int i = tid; i < cnt; i += 256) pb[i] = coarse[(size_t)b * ECAP + i];
    hist[tid] = 0;
    int part = 0;                                  // global base = prefix of ccnt[0..b)
    for (int j = tid; j < b; j += 256) { int c = ccnt[j]; part += c > ECAP ? ECAP : c; }
    red[tid] = part;
    __syncthreads();

    for (int i = tid; i < cnt; i += 256) atomicAdd(&hist[pb[i].y & 255], 1);
    for (int off = 128; off; off >>= 1) {          // reduce red -> gb
        if (tid < off) red[tid] += red[tid + off];
        __syncthreads();
    }
    int gb = red[0];
    int h0 = hist[tid];
    epfx[tid] = h0;                                // inclusive Hillis-Steele scan
    __syncthreads();
    for (int off = 1; off < 256; off <<= 1) {
        int u = (tid >= off) ? epfx[tid - off] : 0;
        __syncthreads();
        if (tid >= off) epfx[tid] += u;
        __syncthreads();
    }
    int excl = epfx[tid] - h0;
    int g = b * 256 + tid;
    if (g < N) rp[g] = gb + excl;
    if (b == NB - 1 && tid == 255) rp[N] = gb + epfx[255];

    slot[tid] = 0;
    __syncthreads();                               // protect epfx reads below
    epfx[tid] = excl;
    __syncthreads();
    for (int i = tid; i < cnt; i += 256) {
        int l = pb[i].y & 255;
        int p = atomicAdd(&slot[l], 1);
        csr[gb + epfx[l] + p] = pb[i].x;
    }
}

// ---- GEMM2 fused with CSR mean-gather (r1 fused structure, best measured;
// replica compaction deleted — indices come from dense CSR, 1-2 lines/row).
__global__ __launch_bounds__(256) void k_gemm2(
    const unsigned short* __restrict__ xfb,
    const int* __restrict__ rp, const int* __restrict__ csr,
    const unsigned short* __restrict__ Btl, const unsigned short* __restrict__ Btr,
    const float* __restrict__ lin_l_b, const float* __restrict__ sh_w,
    const float* __restrict__ rer, const float* __restrict__ d1,
    const float* __restrict__ scal, float* __restrict__ out, int N) {
    __shared__ unsigned short agg[64 * LDSPITCH];
    int lane = threadIdx.x & 63;
    int wv = threadIdx.x >> 6;
    int li = lane & 15, q = lane >> 4;
    int wrow0 = blockIdx.x * 64 + wv * 16;
    int Nm1 = N - 1;

    // ---- hoist: rp pairs, then first-8 CSR indices, afx prefetch in the gap
    int rowc[4];
#pragma unroll
    for (int rr = 0; rr < 4; ++rr) {
        int row = wrow0 + rr * 4 + q;
        rowc[rr] = row < Nm1 ? row : Nm1;
    }
    int bse[4], dgq[4];
#pragma unroll
    for (int rr = 0; rr < 4; ++rr) {
        bse[rr] = rp[rowc[rr]];
        dgq[rr] = rp[rowc[rr] + 1] - bse[rr];
    }
    int arow = wrow0 + li; if (arow > Nm1) arow = Nm1;
    s16x8 afx[4];
#pragma unroll
    for (int ks = 0; ks < 4; ++ks)
        afx[ks] = *(const s16x8*)(xfb + (size_t)arow * D + ks * 32 + q * 8);
    int ix[4][8];
#pragma unroll
    for (int rr = 0; rr < 4; ++rr)
#pragma unroll
        for (int k = 0; k < 8; ++k)
            ix[rr][k] = csr[bse[rr] + k];          // unconditional: csr padded +32

    // ---- gather: branch-free first batch of 8 for all 4 rows ----
    float t[4][8];
#pragma unroll
    for (int rr = 0; rr < 4; ++rr)
#pragma unroll
        for (int k2 = 0; k2 < 8; ++k2) t[rr][k2] = 0.f;

#pragma unroll
    for (int rr = 0; rr < 4; ++rr) {
        int dg = dgq[rr];
        s16x8 v[8];
#pragma unroll
        for (int k = 0; k < 8; ++k) {
            int c = ix[rr][k];                     // garbage past dg: clamp -> safe
            c = c > 0 ? c : 0;
            c = c < Nm1 ? c : Nm1;
            v[k] = *(const s16x8*)(xfb + (size_t)c * D + li * 8);
        }
        float w[8];
#pragma unroll
        for (int k = 0; k < 8; ++k) w[k] = (k < dg) ? 1.f : 0.f;
#pragma unroll
        for (int k = 0; k < 8; ++k)
#pragma unroll
            for (int k2 = 0; k2 < 8; ++k2)
                t[rr][k2] += w[k] * b2f((unsigned short)v[k][k2]);
    }

    // ---- rare cleanup: deg > 8 (~15% of rows), exec-masked ----
#pragma unroll
    for (int rr = 0; rr < 4; ++rr) {
        int dg = dgq[rr];
        if (dg > 8) {
            for (int j = 8; j < dg; j += 8) {
                int jx[8];
#pragma unroll
                for (int k = 0; k < 8; ++k) jx[k] = csr[bse[rr] + j + k];  // padded
                s16x8 v[8];
#pragma unroll
                for (int k = 0; k < 8; ++k) {
                    int c = jx[k];
                    c = c > 0 ? c : 0;
                    c = c < Nm1 ? c : Nm1;
                    v[k] = *(const s16x8*)(xfb + (size_t)c * D + li * 8);
                }
                float w[8];
#pragma unroll
                for (int k = 0; k < 8; ++k) w[k] = (j + k < dg) ? 1.f : 0.f;
#pragma unroll
                for (int k = 0; k < 8; ++k)
#pragma unroll
                    for (int k2 = 0; k2 < 8; ++k2)
                        t[rr][k2] += w[k] * b2f((unsigned short)v[k][k2]);
            }
        }
    }

    // ---- normalize + LDS transpose staging ----
#pragma unroll
    for (int rr = 0; rr < 4; ++rr) {
        int dg = dgq[rr];
        float rc = 1.0f / (float)(dg > 0 ? dg : 1);
        s16x8 o;
#pragma unroll
        for (int k2 = 0; k2 < 8; ++k2) o[k2] = (short)f2b(t[rr][k2] * rc);
        *(s16x8*)(agg + (wv * 16 + rr * 4 + q) * LDSPITCH + li * 8) = o;
    }
    // no __syncthreads: each wave writes and reads only its own 16 LDS rows

    f32x4 acc[8];
#pragma unroll
    for (int nt = 0; nt < 8; ++nt) acc[nt] = (f32x4){0.f, 0.f, 0.f, 0.f};

    // merged phases: per ks, load 8 B-frags, fire 8 MFMAs, repeat for lin_r
#pragma unroll
    for (int ks = 0; ks < 4; ++ks) {
        s16x8 afa = *(const s16x8*)(agg + (wv * 16 + li) * LDSPITCH + ks * 32 + q * 8);
        s16x8 bfl[8];
#pragma unroll
        for (int nt = 0; nt < 8; ++nt)
            bfl[nt] = *(const s16x8*)(Btl + (size_t)(nt * 16 + li) * D + ks * 32 + q * 8);
#pragma unroll
        for (int nt = 0; nt < 8; ++nt)
            acc[nt] = __builtin_amdgcn_mfma_f32_16x16x32_bf16(afa, bfl[nt], acc[nt], 0, 0, 0);
        s16x8 bfr[8];
#pragma unroll
        for (int nt = 0; nt < 8; ++nt)
            bfr[nt] = *(const s16x8*)(Btr + (size_t)(nt * 16 + li) * D + ks * 32 + q * 8);
#pragma unroll
        for (int nt = 0; nt < 8; ++nt)
            acc[nt] = __builtin_amdgcn_mfma_f32_16x16x32_bf16(afx[ks], bfr[nt], acc[nt], 0, 0, 0);
    }

    float a = scal[0], c0 = scal[1];
    float sdot[4] = {0.f, 0.f, 0.f, 0.f};
#pragma unroll
    for (int nt = 0; nt < 8; ++nt) {
        int n = nt * 16 + li;
        float bias = lin_l_b[n];
        float shw = sh_w[n];
#pragma unroll
        for (int r = 0; r < 4; ++r) {
            float tt = acc[nt][r] + bias;
            sdot[r] += fmaxf(tt, 0.f) * shw;
        }
    }
#pragma unroll
    for (int r = 0; r < 4; ++r) {
        float s = sdot[r];
        s += __shfl_xor(s, 1, 64);
        s += __shfl_xor(s, 2, 64);
        s += __shfl_xor(s, 4, 64);
        s += __shfl_xor(s, 8, 64);
        if (li == 0) {
            int rr = wrow0 + q * 4 + r;
            if (rr < N) out[rr] = a * rer[rr] + (1.f - a) * (c0 + d1[rr] + s);
        }
    }
}

extern "C" void kernel_launch(void* const* d_in, const int* in_sizes, int n_in,
                              void* d_out, int out_size, void* d_ws, size_t ws_size,
                              hipStream_t stream) {
    const float* x        = (const float*)d_in[0];
    const int*   positions= (const int*)d_in[1];
    const int*   lengths  = (const int*)d_in[2];
    const int*   ei       = (const int*)d_in[3];
    const float* rer      = (const float*)d_in[4];
    const float* fp_w     = (const float*)d_in[5];
    const float* fp_b     = (const float*)d_in[6];
    const float* lin_l_w  = (const float*)d_in[7];
    const float* lin_l_b  = (const float*)d_in[8];
    const float* lin_r_w  = (const float*)d_in[9];
    const float* res_w    = (const float*)d_in[10];
    const float* res_b    = (const float*)d_in[11];
    const float* sh_w     = (const float*)d_in[12];
    const float* sh_b     = (const float*)d_in[13];
    const float* alpha    = (const float*)d_in[14];
    int N = in_sizes[1];
    int E = in_sizes[3] / 2;
    float* out = (float*)d_out;

    int NB = (N + 255) >> 8;          // coarse buckets of 256 nodes

    char* ws = (char*)d_ws;
    size_t off = 0;
    auto alloc = [&](size_t bytes) -> void* {
        void* p = ws + off;
        off = (off + bytes + 255) & ~(size_t)255;
        return p;
    };
    unsigned short* xb  = (unsigned short*)alloc((size_t)N * D * 2);
    int2* coarse = (int2*)alloc((size_t)NB * ECAP * 8);
    int* ccnt    = (int*)alloc((size_t)NB * 4);
    int* csr     = (int*)alloc(((size_t)E + 64) * 4);   // +pad for unconditional reads
    int* rp      = (int*)alloc(((size_t)N + 1) * 4);
    float* d1    = (float*)alloc((size_t)N * 4);
    unsigned short* Btf = (unsigned short*)alloc(D * D * 2);
    unsigned short* Btl = (unsigned short*)alloc(D * D * 2);
    unsigned short* Btr = (unsigned short*)alloc(D * D * 2);
    float* c1    = (float*)alloc(D * 4);
    float* scal  = (float*)alloc(16);

    int mb = (N + 63) / 64;
    int cb = (E + 255) / 256;

    k_prep<<<193, 256, 0, stream>>>(fp_w, lin_l_w, lin_r_w, Btf, Btl, Btr,
                                    res_w, res_b, sh_w, sh_b, alpha, c1, scal,
                                    ccnt, NB);
    k_gemm1<<<mb + cb, 256, 0, stream>>>(x, xb, positions, lengths, Btf, fp_w, fp_b,
                                         c1, d1, N, mb, ei, ccnt, coarse, E);
    k_bucket<<<NB, 256, 0, stream>>>(coarse, ccnt, csr, rp, NB, N);
    k_gemm2<<<mb, 256, 0, stream>>>(xb, rp, csr, Btl, Btr, lin_l_b, sh_w, rer, d1, scal, out, N);
}

// Round 7
// 261.006 us; speedup vs baseline: 1.6625x; 1.6625x over previous
//
#include <hip/hip_runtime.h>
#include <hip/hip_bf16.h>
#include <cstdint>

#define D 128
#define LDSPITCH 136   // shorts; 272B row stride: 16B-aligned, banks uniform
#define LB 64          // nodes per bucket == gemm2 tile rows
#define DCAP 32        // per-node dense list cap (Poisson(6): P(>32) ~ 1e-13)
#define NBLK 64        // edge chunks for the counting sort
#define NBMAX 2048     // LDS bound on bucket count (N=100k -> NB=1563)

typedef __attribute__((ext_vector_type(4))) float f32x4;
typedef __attribute__((ext_vector_type(8))) short s16x8;

__device__ __forceinline__ unsigned short f2b(float f) {
    union { float f; uint32_t u; } v; v.f = f;
    uint32_t b = v.u + 0x7fffu + ((v.u >> 16) & 1u);   // RNE
    return (unsigned short)(b >> 16);
}
__device__ __forceinline__ float b2f(unsigned short u) {
    union { uint32_t u; float f; } v; v.u = ((uint32_t)u) << 16; return v.f;
}

// ---- prep: [0,192) transpose+bf16 weights; 192: consts;
// [193,193+NBLK): counting-sort pass A — per-chunk LDS histogram of dst>>6.
// No device atomics anywhere in the sort (r6 lesson: hot-line atomics 3x'd
// the kernel; r0-r5: random-line atomics/scatter cost ~37MB line-granule
// write traffic). Deterministic offsets instead.
__global__ __launch_bounds__(256) void k_prep(
    const float* __restrict__ fp_w, const float* __restrict__ lin_l_w,
    const float* __restrict__ lin_r_w,
    unsigned short* __restrict__ Btf, unsigned short* __restrict__ Btl,
    unsigned short* __restrict__ Btr,
    const float* __restrict__ res_w, const float* __restrict__ res_b,
    const float* __restrict__ sh_w, const float* __restrict__ sh_b,
    const float* __restrict__ alpha, float* __restrict__ c1, float* __restrict__ scal,
    const int* __restrict__ ei, int* __restrict__ histg, int E, int EBLK, int NB) {
    __shared__ int h[NBMAX];
    int bid = blockIdx.x, tid = threadIdx.x;
    if (bid < 192) {
        int m = bid >> 6;
        int i = (bid & 63) * 256 + tid;
        const float* src = (m == 0) ? fp_w : (m == 1) ? lin_l_w : lin_r_w;
        unsigned short* dst = (m == 0) ? Btf : (m == 1) ? Btl : Btr;
        int k = i >> 7, n = i & 127;
        dst[n * D + k] = f2b(src[k * D + n]);
    } else if (bid == 192) {
        if (tid < 128) {
            float s = 0.f;
            for (int j = 0; j < D; ++j) s += res_w[tid * D + j] * sh_w[j];
            c1[tid] = s;
            if (tid == 0) {
                float c0 = 0.f;
                for (int j = 0; j < D; ++j) c0 += res_b[j] * sh_w[j];
                c0 += sh_b[0];
                float a = 1.f / (1.f + expf(-alpha[0]));
                scal[0] = a; scal[1] = c0;
            }
        }
    } else {
        int k = bid - 193;                 // edge chunk id
        for (int j = tid; j < NB; j += 256) h[j] = 0;
        __syncthreads();
        int s = k * EBLK, e = s + EBLK; if (e > E) e = E;
        for (int i = s + tid; i < e; i += 256)
            atomicAdd(&h[ei[E + i] >> 6], 1);          // LDS atomic only
        __syncthreads();
        for (int j = tid; j < NB; j += 256) histg[j * NBLK + k] = h[j];
    }
}

// ---- scan 1: per-bucket exclusive scan over its NBLK chunk counts (in place);
// total[b] = bucket size. One thread per bucket.
__global__ __launch_bounds__(256) void k_scan1(
    int* __restrict__ histg, int* __restrict__ total, int NB) {
    int b = blockIdx.x * 256 + threadIdx.x;
    if (b >= NB) return;
    int* p = histg + (size_t)b * NBLK;
    int run = 0;
#pragma unroll 8
    for (int k = 0; k < NBLK; ++k) { int t = p[k]; p[k] = run; run += t; }
    total[b] = run;
}

// ---- scan 2: exclusive scan of bucket totals -> base[]; base[NB] = E.
__global__ __launch_bounds__(256) void k_scan2(
    const int* __restrict__ total, int* __restrict__ base, int NB) {
    __shared__ int sh[256];
    int tid = threadIdx.x;
    int carry = 0;
    int nch = (NB + 255) >> 8;
    for (int c = 0; c < nch; ++c) {
        int idx = c * 256 + tid;
        int v = idx < NB ? total[idx] : 0;
        sh[tid] = v;
        __syncthreads();
        for (int off = 1; off < 256; off <<= 1) {      // inclusive Hillis-Steele
            int u = (tid >= off) ? sh[tid - off] : 0;
            __syncthreads();
            if (tid >= off) sh[tid] += u;
            __syncthreads();
        }
        if (idx < NB) base[idx] = carry + sh[tid] - v; // exclusive
        int chtot = sh[255];
        __syncthreads();                               // protect sh before reuse
        carry += chtot;
    }
    if (tid == 0) base[NB] = carry;                    // == E
}

// ---- GEMM1 (+ counting-sort pass C piggy-backed):
// blocks [0,mb): xf = [x|pos|len] @ fp_w + fp_b -> bf16 xb; d1 = xf.c1
// blocks [mb,..): scatter edges to exact per-(chunk,bucket) ranges. LDS
// cursors seeded with base[b]+histg[b][k]; ranges are disjoint by
// construction -> zero device-atomic contention; writes land in a 2.4MB
// L2-resident fully-covered region (line-local).
__global__ __launch_bounds__(256) void k_gemm1(
    const float* __restrict__ x, unsigned short* __restrict__ xb,
    const int* __restrict__ positions, const int* __restrict__ lengths,
    const unsigned short* __restrict__ Btf,
    const float* __restrict__ fp_w, const float* __restrict__ fp_b,
    const float* __restrict__ c1, float* __restrict__ d1, int N, int mb,
    const int* __restrict__ ei, const int* __restrict__ histg,
    const int* __restrict__ base, int* __restrict__ coarse, int E, int EBLK, int NB) {
    __shared__ int cur[NBMAX];
    if (blockIdx.x >= mb) {
        int tid = threadIdx.x;
        int k = blockIdx.x - mb;
        for (int j = tid; j < NB; j += 256)
            cur[j] = base[j] + histg[(size_t)j * NBLK + k];
        __syncthreads();
        int s = k * EBLK, e = s + EBLK; if (e > E) e = E;
        for (int i = s + tid; i < e; i += 256) {
            int sv = ei[i];
            int d  = ei[E + i];
            int p = atomicAdd(&cur[d >> 6], 1);        // LDS atomic only
            coarse[p] = sv | ((d & 63) << 17);         // src<2^17; pack local dst
        }
        return;
    }
    int lane = threadIdx.x & 63;
    int wv = threadIdx.x >> 6;
    int col = lane & 15, q = lane >> 4;
    int row0 = blockIdx.x * 64 + wv * 16;
    int arow = row0 + col; if (arow > N - 1) arow = N - 1;

    f32x4 acc[8];
#pragma unroll
    for (int nt = 0; nt < 8; ++nt) acc[nt] = (f32x4){0.f, 0.f, 0.f, 0.f};

#pragma unroll
    for (int ks = 0; ks < 4; ++ks) {
        const float* xp = x + (size_t)arow * D + ks * 32 + q * 8;
        float4 a0 = *(const float4*)xp;
        float4 a1 = *(const float4*)(xp + 4);
        s16x8 af;
        af[0] = (short)f2b(a0.x); af[1] = (short)f2b(a0.y);
        af[2] = (short)f2b(a0.z); af[3] = (short)f2b(a0.w);
        af[4] = (short)f2b(a1.x); af[5] = (short)f2b(a1.y);
        af[6] = (short)f2b(a1.z); af[7] = (short)f2b(a1.w);
#pragma unroll
        for (int nt = 0; nt < 8; ++nt) {
            s16x8 bf = *(const s16x8*)(Btf + (size_t)(nt * 16 + col) * D + ks * 32 + q * 8);
            acc[nt] = __builtin_amdgcn_mfma_f32_16x16x32_bf16(af, bf, acc[nt], 0, 0, 0);
        }
    }

    float pf[4], lf[4];
#pragma unroll
    for (int r = 0; r < 4; ++r) {
        int rr = row0 + q * 4 + r; int rc = rr < N ? rr : N - 1;
        pf[r] = (float)positions[rc] * (1.0f / 50.0f);
        lf[r] = (float)lengths[rc] * (1.0f / 500.0f);
    }
    float sdot[4] = {0.f, 0.f, 0.f, 0.f};
#pragma unroll
    for (int nt = 0; nt < 8; ++nt) {
        int n = nt * 16 + col;
        float bias = fp_b[n];
        float w128 = fp_w[128 * D + n];
        float w129 = fp_w[129 * D + n];
        float c1v = c1[n];
#pragma unroll
        for (int r = 0; r < 4; ++r) {
            float t = acc[nt][r] + bias + pf[r] * w128 + lf[r] * w129;
            int rr = row0 + q * 4 + r;
            if (rr < N) xb[(size_t)rr * D + n] = f2b(t);
            sdot[r] += t * c1v;
        }
    }
#pragma unroll
    for (int r = 0; r < 4; ++r) {
        float s = sdot[r];
        s += __shfl_xor(s, 1, 64);
        s += __shfl_xor(s, 2, 64);
        s += __shfl_xor(s, 4, 64);
        s += __shfl_xor(s, 8, 64);
        if (col == 0) {
            int rr = row0 + q * 4 + r;
            if (rr < N) d1[rr] = s;
        }
    }
}

// ---- GEMM2 fused with bucket mean-gather. Block bx == bucket bx (64 nodes):
// its edges sit CONTIGUOUS at coarse[base[bx]..base[bx+1]). Tiny LDS binning
// (~1.5 iter) builds dense[64][32]; then the proven r1 gather/MFMA body runs
// with indices from LDS. Exact degrees, no global index scatter to re-read.
__global__ __launch_bounds__(256) void k_gemm2(
    const unsigned short* __restrict__ xfb,
    const int* __restrict__ base, const int* __restrict__ coarse,
    const unsigned short* __restrict__ Btl, const unsigned short* __restrict__ Btr,
    const float* __restrict__ lin_l_b, const float* __restrict__ sh_w,
    const float* __restrict__ rer, const float* __restrict__ d1,
    const float* __restrict__ scal, float* __restrict__ out, int N) {
    __shared__ unsigned short agg[64 * LDSPITCH];
    __shared__ int dense[64][DCAP];
    __shared__ int cnt64[64];
    int tid = threadIdx.x;
    int lane = tid & 63;
    int wv = tid >> 6;
    int li = lane & 15, q = lane >> 4;
    int wrow0 = blockIdx.x * 64 + wv * 16;
    int Nm1 = N - 1;

    // phase-B A-operand prefetch early (independent, long-latency)
    int arow = wrow0 + li; if (arow > Nm1) arow = Nm1;
    s16x8 afx[4];
#pragma unroll
    for (int ks = 0; ks < 4; ++ks)
        afx[ks] = *(const s16x8*)(xfb + (size_t)arow * D + ks * 32 + q * 8);

    // ---- binning: contiguous coalesced read of this bucket's packed pairs
    int b0 = base[blockIdx.x], cnt = base[blockIdx.x + 1] - b0;
    if (tid < 64) cnt64[tid] = 0;
    __syncthreads();
    for (int i = tid; i < cnt; i += 256) {
        int v = coarse[b0 + i];
        int l = v >> 17;                       // local dst (v < 2^23, no sign)
        int p = atomicAdd(&cnt64[l], 1);
        if (p < DCAP) dense[l][p] = v & 0x1ffff;
    }
    __syncthreads();

    // ---- gather: branch-free first batch of 8 for all 4 rows ----
    float t[4][8];
#pragma unroll
    for (int rr = 0; rr < 4; ++rr)
#pragma unroll
        for (int k2 = 0; k2 < 8; ++k2) t[rr][k2] = 0.f;

    int dgq[4];
#pragma unroll
    for (int rr = 0; rr < 4; ++rr) {
        int dg = cnt64[wv * 16 + rr * 4 + q];
        dgq[rr] = dg > DCAP ? DCAP : dg;       // old truncation semantics
    }

#pragma unroll
    for (int rr = 0; rr < 4; ++rr) {
        int dg = dgq[rr];
        const int* dr = &dense[wv * 16 + rr * 4 + q][0];
        int4 ja = *(const int4*)dr;            // LDS reads, 16B aligned
        int4 jb = *(const int4*)(dr + 4);
        int ix[8] = {ja.x, ja.y, ja.z, ja.w, jb.x, jb.y, jb.z, jb.w};
        s16x8 v[8];
#pragma unroll
        for (int k = 0; k < 8; ++k) {
            int c = ix[k];                     // garbage past dg: clamp -> safe
            c = c > 0 ? c : 0;
            c = c < Nm1 ? c : Nm1;
            v[k] = *(const s16x8*)(xfb + (size_t)c * D + li * 8);
        }
        float w[8];
#pragma unroll
        for (int k = 0; k < 8; ++k) w[k] = (k < dg) ? 1.f : 0.f;
#pragma unroll
        for (int k = 0; k < 8; ++k)
#pragma unroll
            for (int k2 = 0; k2 < 8; ++k2)
                t[rr][k2] += w[k] * b2f((unsigned short)v[k][k2]);
    }

    // ---- rare cleanup: deg > 8 (~15% of rows), exec-masked ----
#pragma unroll
    for (int rr = 0; rr < 4; ++rr) {
        int dg = dgq[rr];
        if (dg > 8) {
            const int* dr = &dense[wv * 16 + rr * 4 + q][0];
            for (int j = 8; j < dg; j += 8) {  // j in {8,16,24}: j+7 < DCAP
                int4 jc = *(const int4*)(dr + j);
                int4 jd = *(const int4*)(dr + j + 4);
                int ix[8] = {jc.x, jc.y, jc.z, jc.w, jd.x, jd.y, jd.z, jd.w};
                s16x8 v[8];
#pragma unroll
                for (int k = 0; k < 8; ++k) {
                    int c = ix[k];
                    c = c > 0 ? c : 0;
                    c = c < Nm1 ? c : Nm1;
                    v[k] = *(const s16x8*)(xfb + (size_t)c * D + li * 8);
                }
                float w[8];
#pragma unroll
                for (int k = 0; k < 8; ++k) w[k] = (j + k < dg) ? 1.f : 0.f;
#pragma unroll
                for (int k = 0; k < 8; ++k)
#pragma unroll
                    for (int k2 = 0; k2 < 8; ++k2)
                        t[rr][k2] += w[k] * b2f((unsigned short)v[k][k2]);
            }
        }
    }

    // ---- normalize + LDS transpose staging (wave-local, no barrier) ----
#pragma unroll
    for (int rr = 0; rr < 4; ++rr) {
        int dg = dgq[rr];
        float rc = 1.0f / (float)(dg > 0 ? dg : 1);
        s16x8 o;
#pragma unroll
        for (int k2 = 0; k2 < 8; ++k2) o[k2] = (short)f2b(t[rr][k2] * rc);
        *(s16x8*)(agg + (wv * 16 + rr * 4 + q) * LDSPITCH + li * 8) = o;
    }

    f32x4 acc[8];
#pragma unroll
    for (int nt = 0; nt < 8; ++nt) acc[nt] = (f32x4){0.f, 0.f, 0.f, 0.f};

    // merged phases: per ks, load 8 B-frags, fire 8 MFMAs, repeat for lin_r
#pragma unroll
    for (int ks = 0; ks < 4; ++ks) {
        s16x8 afa = *(const s16x8*)(agg + (wv * 16 + li) * LDSPITCH + ks * 32 + q * 8);
        s16x8 bfl[8];
#pragma unroll
        for (int nt = 0; nt < 8; ++nt)
            bfl[nt] = *(const s16x8*)(Btl + (size_t)(nt * 16 + li) * D + ks * 32 + q * 8);
#pragma unroll
        for (int nt = 0; nt < 8; ++nt)
            acc[nt] = __builtin_amdgcn_mfma_f32_16x16x32_bf16(afa, bfl[nt], acc[nt], 0, 0, 0);
        s16x8 bfr[8];
#pragma unroll
        for (int nt = 0; nt < 8; ++nt)
            bfr[nt] = *(const s16x8*)(Btr + (size_t)(nt * 16 + li) * D + ks * 32 + q * 8);
#pragma unroll
        for (int nt = 0; nt < 8; ++nt)
            acc[nt] = __builtin_amdgcn_mfma_f32_16x16x32_bf16(afx[ks], bfr[nt], acc[nt], 0, 0, 0);
    }

    float a = scal[0], c0 = scal[1];
    float sdot[4] = {0.f, 0.f, 0.f, 0.f};
#pragma unroll
    for (int nt = 0; nt < 8; ++nt) {
        int n = nt * 16 + li;
        float bias = lin_l_b[n];
        float shw = sh_w[n];
#pragma unroll
        for (int r = 0; r < 4; ++r) {
            float tt = acc[nt][r] + bias;
            sdot[r] += fmaxf(tt, 0.f) * shw;
        }
    }
#pragma unroll
    for (int r = 0; r < 4; ++r) {
        float s = sdot[r];
        s += __shfl_xor(s, 1, 64);
        s += __shfl_xor(s, 2, 64);
        s += __shfl_xor(s, 4, 64);
        s += __shfl_xor(s, 8, 64);
        if (li == 0) {
            int rr = wrow0 + q * 4 + r;
            if (rr < N) out[rr] = a * rer[rr] + (1.f - a) * (c0 + d1[rr] + s);
        }
    }
}

extern "C" void kernel_launch(void* const* d_in, const int* in_sizes, int n_in,
                              void* d_out, int out_size, void* d_ws, size_t ws_size,
                              hipStream_t stream) {
    const float* x        = (const float*)d_in[0];
    const int*   positions= (const int*)d_in[1];
    const int*   lengths  = (const int*)d_in[2];
    const int*   ei       = (const int*)d_in[3];
    const float* rer      = (const float*)d_in[4];
    const float* fp_w     = (const float*)d_in[5];
    const float* fp_b     = (const float*)d_in[6];
    const float* lin_l_w  = (const float*)d_in[7];
    const float* lin_l_b  = (const float*)d_in[8];
    const float* lin_r_w  = (const float*)d_in[9];
    const float* res_w    = (const float*)d_in[10];
    const float* res_b    = (const float*)d_in[11];
    const float* sh_w     = (const float*)d_in[12];
    const float* sh_b     = (const float*)d_in[13];
    const float* alpha    = (const float*)d_in[14];
    int N = in_sizes[1];
    int E = in_sizes[3] / 2;
    float* out = (float*)d_out;

    int NB = (N + LB - 1) / LB;        // 64-node buckets == gemm2 tiles
    int EBLK = (E + NBLK - 1) / NBLK;  // edges per sort chunk
    int mb = (N + 63) / 64;

    char* ws = (char*)d_ws;
    size_t off = 0;
    auto alloc = [&](size_t bytes) -> void* {
        void* p = ws + off;
        off = (off + bytes + 255) & ~(size_t)255;
        return p;
    };
    unsigned short* xb  = (unsigned short*)alloc((size_t)N * D * 2);
    int* coarse  = (int*)alloc(((size_t)E + 64) * 4);
    int* histg   = (int*)alloc((size_t)NB * NBLK * 4);
    int* total   = (int*)alloc((size_t)NB * 4);
    int* base    = (int*)alloc(((size_t)NB + 1) * 4);
    float* d1    = (float*)alloc((size_t)N * 4);
    unsigned short* Btf = (unsigned short*)alloc(D * D * 2);
    unsigned short* Btl = (unsigned short*)alloc(D * D * 2);
    unsigned short* Btr = (unsigned short*)alloc(D * D * 2);
    float* c1    = (float*)alloc(D * 4);
    float* scal  = (float*)alloc(16);

    k_prep<<<193 + NBLK, 256, 0, stream>>>(fp_w, lin_l_w, lin_r_w, Btf, Btl, Btr,
                                           res_w, res_b, sh_w, sh_b, alpha, c1, scal,
                                           ei, histg, E, EBLK, NB);
    k_scan1<<<(NB + 255) / 256, 256, 0, stream>>>(histg, total, NB);
    k_scan2<<<1, 256, 0, stream>>>(total, base, NB);
    k_gemm1<<<mb + NBLK, 256, 0, stream>>>(x, xb, positions, lengths, Btf, fp_w, fp_b,
                                           c1, d1, N, mb, ei, histg, base, coarse,
                                           E, EBLK, NB);
    k_gemm2<<<mb, 256, 0, stream>>>(xb, base, coarse, Btl, Btr, lin_l_b, sh_w,
                                    rer, d1, scal, out, N);
}